// Round 1
// baseline (588.922 us; speedup 1.0000x reference)
//
#include <hip/hip_runtime.h>

// RSWAF: out[..., g] = 1 - tanh((x - grid[g]) * inv_den)^2
//      = sech^2(y) = 4u / (1+u)^2,  u = exp(-2|y|)  (exact rewrite, no overflow)
// Memory-bound: 512 MiB out + 64 MiB in. Each thread -> one float4 of output
// (4 consecutive grid values), perfectly coalesced 16 B/lane stores.

__global__ __launch_bounds__(256) void rswaf_kernel(
    const float* __restrict__ x,
    const float* __restrict__ grid,   // 8 floats
    const float* __restrict__ inv_den_p,
    float4* __restrict__ out,
    int n4)                           // number of float4 outputs
{
    int tid = blockIdx.x * blockDim.x + threadIdx.x;
    if (tid >= n4) return;

    // c = 2 * log2(e) * |inv_den|  (uniform; scalar-loaded/computed once)
    const float c = fabsf(inv_den_p[0]) * 2.8853900817779268f;

    // out elements [4*tid, 4*tid+4): x index = (4*tid)/8 = tid>>1,
    // grid offset = (4*tid)%8 = (tid&1)*4 -> aligned float4 of grid.
    const float xi = x[tid >> 1];
    const float4 g = ((const float4*)grid)[tid & 1];

    float4 r;
    {
        float d0 = fabsf(xi - g.x);
        float d1 = fabsf(xi - g.y);
        float d2 = fabsf(xi - g.z);
        float d3 = fabsf(xi - g.w);
        float u0 = __builtin_amdgcn_exp2f(-c * d0);
        float u1 = __builtin_amdgcn_exp2f(-c * d1);
        float u2 = __builtin_amdgcn_exp2f(-c * d2);
        float u3 = __builtin_amdgcn_exp2f(-c * d3);
        float t0 = 1.0f + u0, t1 = 1.0f + u1, t2 = 1.0f + u2, t3 = 1.0f + u3;
        r.x = 4.0f * u0 * __builtin_amdgcn_rcpf(t0 * t0);
        r.y = 4.0f * u1 * __builtin_amdgcn_rcpf(t1 * t1);
        r.z = 4.0f * u2 * __builtin_amdgcn_rcpf(t2 * t2);
        r.w = 4.0f * u3 * __builtin_amdgcn_rcpf(t3 * t3);
    }
    out[tid] = r;
}

extern "C" void kernel_launch(void* const* d_in, const int* in_sizes, int n_in,
                              void* d_out, int out_size, void* d_ws, size_t ws_size,
                              hipStream_t stream) {
    const float* x       = (const float*)d_in[0];   // 16*64*128*128 fp32
    const float* grid    = (const float*)d_in[1];   // 8 fp32
    const float* inv_den = (const float*)d_in[2];   // 1 fp32
    float* out = (float*)d_out;                     // out_size = 8 * nx

    const int n4 = out_size / 4;                    // float4 outputs
    const int block = 256;
    const int nblocks = (n4 + block - 1) / block;
    rswaf_kernel<<<nblocks, block, 0, stream>>>(x, grid, inv_den,
                                                (float4*)out, n4);
}